// Round 1
// baseline (284.613 us; speedup 1.0000x reference)
//
#include <hip/hip_runtime.h>
#include <math.h>

#define B 8
#define T 128
#define NKEY 127   // t-1
#define KDIM 64    // Q_DIM == KV_DIM
#define NH 4       // heads
#define CH 256     // NH*KDIM output channels

// Fast tanh via hw v_exp_f32: tanh(x) = (e^{2x}-1)/(e^{2x}+1), clamp to avoid inf/inf.
__device__ __forceinline__ float fast_tanh(float x) {
    float xc = fminf(fmaxf(x, -10.f), 10.f);
    float e = __expf(2.f * xc);
    return (e - 1.f) / (e + 1.f);
}

// One workgroup per (b,t): 256 threads = 4 waves; wave w == head w; lane == channel k.
__global__ __launch_bounds__(256)
void attn_kernel(const float* __restrict__ q_x,   // (B,T,64)
                 const float* __restrict__ kv_x,  // (B,T,127,64)
                 const float* __restrict__ Wk,    // (256,64)
                 const float* __restrict__ Wq,    // (256,64)
                 const float* __restrict__ Wv,    // (256,64)
                 const float* __restrict__ bias,  // (64,)
                 const float* __restrict__ Ws,    // (1,64)
                 const float* __restrict__ bs,    // (1,)
                 float* __restrict__ out)         // (B,T,256)
{
    __shared__ float kv_lds[NKEY][KDIM];   // 32512 B
    __shared__ float q_lds[KDIM];          // 256 B

    const int bt   = blockIdx.x;           // 0..1023  == b*T + t
    const int tid  = threadIdx.x;          // 0..255   == output channel j = h*64 + k
    const int lane = tid & 63;             // k within head

    // ---- stage q row and full kv tile into LDS (coalesced float4) ----
    if (tid < KDIM) q_lds[tid] = q_x[(size_t)bt * KDIM + tid];
    {
        const float4* src = (const float4*)(kv_x + (size_t)bt * NKEY * KDIM);
        float4* dst = (float4*)(&kv_lds[0][0]);
        const int nvec = NKEY * KDIM / 4;  // 2032
        for (int i = tid; i < nvec; i += 256) dst[i] = src[i];
    }
    __syncthreads();

    // ---- per-thread weight rows ----
    const float4* Wq4 = (const float4*)(Wq + (size_t)tid * KDIM);
    const float4* Wk4 = (const float4*)(Wk + (size_t)tid * KDIM);
    const float4* Wv4 = (const float4*)(Wv + (size_t)tid * KDIM);

    // query_j = q_row . Wq[j]   (Wq regs are dead afterwards; allocator reuses)
    float query;
    {
        float4 wq[16];
        #pragma unroll
        for (int i = 0; i < 16; ++i) wq[i] = Wq4[i];
        float4 qa = {0.f, 0.f, 0.f, 0.f};
        #pragma unroll
        for (int i = 0; i < 16; ++i) {
            float4 q4 = ((const float4*)q_lds)[i];
            qa.x = fmaf(q4.x, wq[i].x, qa.x);
            qa.y = fmaf(q4.y, wq[i].y, qa.y);
            qa.z = fmaf(q4.z, wq[i].z, qa.z);
            qa.w = fmaf(q4.w, wq[i].w, qa.w);
        }
        query = (qa.x + qa.y) + (qa.z + qa.w);
    }

    float4 wk[16], wv[16];
    #pragma unroll
    for (int i = 0; i < 16; ++i) { wk[i] = Wk4[i]; wv[i] = Wv4[i]; }

    const float bias_l = bias[lane];
    const float ws_l   = Ws[lane];
    const float bs_v   = bs[0];

    // ---- main loop over the 127 keys: online softmax ----
    float m = -1e30f, l = 0.f, acc = 0.f;
    for (int n = 0; n < NKEY; ++n) {
        const float4* kv4 = (const float4*)kv_lds[n];  // broadcast reads, no bank conflicts
        float4 ka = {0.f, 0.f, 0.f, 0.f};
        float4 va = {0.f, 0.f, 0.f, 0.f};
        #pragma unroll
        for (int i = 0; i < 16; ++i) {
            float4 c = kv4[i];
            ka.x = fmaf(c.x, wk[i].x, ka.x);
            ka.y = fmaf(c.y, wk[i].y, ka.y);
            ka.z = fmaf(c.z, wk[i].z, ka.z);
            ka.w = fmaf(c.w, wk[i].w, ka.w);
            va.x = fmaf(c.x, wv[i].x, va.x);
            va.y = fmaf(c.y, wv[i].y, va.y);
            va.z = fmaf(c.z, wv[i].z, va.z);
            va.w = fmaf(c.w, wv[i].w, va.w);
        }
        const float key = (ka.x + ka.y) + (ka.z + ka.w);
        const float val = (va.x + va.y) + (va.z + va.w);

        // per-lane score contribution, then 64-lane butterfly sum (head == wave)
        float partial = fast_tanh(key + query + bias_l) * ws_l;
        #pragma unroll
        for (int off = 32; off > 0; off >>= 1)
            partial += __shfl_xor(partial, off, 64);
        const float s = partial + bs_v;

        // online softmax update (identical across the wave's 64 lanes)
        const float m_new  = fmaxf(m, s);
        const float alpha  = __expf(m - m_new);
        const float p      = __expf(s - m_new);
        l   = l * alpha + p;
        acc = acc * alpha + p * val;
        m   = m_new;
    }

    out[(size_t)bt * CH + tid] = acc / l;
}

extern "C" void kernel_launch(void* const* d_in, const int* in_sizes, int n_in,
                              void* d_out, int out_size, void* d_ws, size_t ws_size,
                              hipStream_t stream) {
    const float* q_x  = (const float*)d_in[0];
    const float* kv_x = (const float*)d_in[1];
    const float* Wk   = (const float*)d_in[2];
    const float* Wq   = (const float*)d_in[3];
    const float* Wv   = (const float*)d_in[4];
    const float* bias = (const float*)d_in[5];
    const float* Ws   = (const float*)d_in[6];
    const float* bs   = (const float*)d_in[7];
    float* out = (float*)d_out;

    attn_kernel<<<dim3(B * T), dim3(256), 0, stream>>>(
        q_x, kv_x, Wk, Wq, Wv, bias, Ws, bs, out);
}

// Round 2
// 266.803 us; speedup vs baseline: 1.0668x; 1.0668x over previous
//
#include <hip/hip_runtime.h>
#include <math.h>

#define B 8
#define T 128
#define NKEY 127   // t-1
#define NPAD 128   // padded key count (row 127 zeroed, prob forced to 0)
#define KDIM 64    // Q_DIM == KV_DIM
#define NH 4       // heads
#define CH 256     // NH*KDIM output channels

// Fast tanh via hw v_exp_f32: tanh(x) = (e^{2x}-1)/(e^{2x}+1), clamp to avoid inf/inf.
__device__ __forceinline__ float fast_tanh(float x) {
    float xc = fminf(fmaxf(x, -10.f), 10.f);
    float e = __expf(2.f * xc);
    return (e - 1.f) / (e + 1.f);
}

// One workgroup per (b,t): 256 threads = 4 waves; wave h == head h; lane == channel k.
// Restructured: (A) keys GEMM + tanh-score (two-pass, batched 8 keys),
// (B) probability-weighted kv reduction (127 FMA), (C) 64-FMA Wv projection.
// Value GEMM eliminated algebraically: out = (sum_n w_n * kv_n) @ Wv_row.
__global__ __launch_bounds__(256)
void attn_kernel(const float* __restrict__ q_x,   // (B,T,64)
                 const float* __restrict__ kv_x,  // (B,T,127,64)
                 const float* __restrict__ Wk,    // (256,64)
                 const float* __restrict__ Wq,    // (256,64)
                 const float* __restrict__ Wv,    // (256,64)
                 const float* __restrict__ bias,  // (64,)
                 const float* __restrict__ Ws,    // (1,64)
                 const float* __restrict__ bs,    // (1,)  -- cancels in softmax
                 float* __restrict__ out)         // (B,T,256)
{
    __shared__ float kv_lds[NPAD][KDIM];   // 32768 B (row 127 zeroed)
    __shared__ float q_lds[KDIM];          // 256 B
    __shared__ float p_lds[NH][NPAD];      // 2048 B: scores, then probabilities
    __shared__ float wkv_lds[NH][KDIM];    // 1024 B: weighted kv row per head

    const int bt   = blockIdx.x;           // b*T + t
    const int tid  = threadIdx.x;          // output channel j = h*64 + k
    const int h    = tid >> 6;
    const int lane = tid & 63;             // k within head

    // ---- stage q row + kv tile (zero the pad row) ----
    if (tid < KDIM) q_lds[tid] = q_x[(size_t)bt * KDIM + tid];
    {
        const float4* src = (const float4*)(kv_x + (size_t)bt * NKEY * KDIM);
        float4* dst = (float4*)(&kv_lds[0][0]);
        for (int i = tid; i < NPAD * KDIM / 4; i += 256) {
            float4 v = make_float4(0.f, 0.f, 0.f, 0.f);
            if (i < NKEY * KDIM / 4) v = src[i];
            dst[i] = v;
        }
    }
    __syncthreads();   // the only barrier: everything after is wave-private

    // ---- per-thread Wk row in registers ----
    float4 wk[16];
    {
        const float4* Wk4 = (const float4*)(Wk + (size_t)tid * KDIM);
        #pragma unroll
        for (int i = 0; i < 16; ++i) wk[i] = Wk4[i];
    }

    // query_j = q_row . Wq[j]
    float query;
    {
        const float4* Wq4 = (const float4*)(Wq + (size_t)tid * KDIM);
        float4 qa = {0.f, 0.f, 0.f, 0.f};
        #pragma unroll
        for (int i = 0; i < 16; ++i) {
            float4 w = Wq4[i];
            float4 q4 = ((const float4*)q_lds)[i];
            qa.x = fmaf(q4.x, w.x, qa.x);
            qa.y = fmaf(q4.y, w.y, qa.y);
            qa.z = fmaf(q4.z, w.z, qa.z);
            qa.w = fmaf(q4.w, w.w, qa.w);
        }
        query = (qa.x + qa.y) + (qa.z + qa.w);
    }

    const float bias_l = bias[lane];
    const float ws_l   = Ws[lane];

    // ---- Phase A: scores for 8 keys at a time (8 independent FMA chains,
    //      8-way-pipelined butterfly reduce over the 64-lane head wave) ----
    for (int n0 = 0; n0 < NPAD; n0 += 8) {
        float s[8] = {0.f, 0.f, 0.f, 0.f, 0.f, 0.f, 0.f, 0.f};
        #pragma unroll
        for (int i = 0; i < 16; ++i) {
            const float4 w = wk[i];
            #pragma unroll
            for (int u = 0; u < 8; ++u) {
                const float4 c = ((const float4*)kv_lds[n0 + u])[i];  // wave-uniform: broadcast
                s[u] = fmaf(c.x, w.x, fmaf(c.y, w.y, fmaf(c.z, w.z, fmaf(c.w, w.w, s[u]))));
            }
        }
        #pragma unroll
        for (int u = 0; u < 8; ++u)
            s[u] = fast_tanh(s[u] + query + bias_l) * ws_l;
        #pragma unroll
        for (int off = 32; off > 0; off >>= 1) {
            #pragma unroll
            for (int u = 0; u < 8; ++u)
                s[u] += __shfl_xor(s[u], off, 64);
        }
        if (lane == 0) {
            float4 a = make_float4(s[0], s[1], s[2], s[3]);
            float4 b = make_float4(s[4], s[5], s[6], s[7]);
            *(float4*)&p_lds[h][n0]     = a;
            *(float4*)&p_lds[h][n0 + 4] = b;
        }
    }
    // no barrier: wave h wrote p_lds[h][*] and is its only reader

    // ---- softmax over the 127 real keys (2 scores per lane) ----
    float invl;
    {
        float s_a = p_lds[h][lane];
        float s_b = p_lds[h][64 + lane];
        if (lane == 63) s_b = -1e30f;          // mask pad row 127
        float mx = fmaxf(s_a, s_b);
        #pragma unroll
        for (int off = 32; off > 0; off >>= 1)
            mx = fmaxf(mx, __shfl_xor(mx, off, 64));
        float pa = __expf(s_a - mx);
        float pb = __expf(s_b - mx);           // lane 63 -> exp(-huge) = 0
        float ls = pa + pb;
        #pragma unroll
        for (int off = 32; off > 0; off >>= 1)
            ls += __shfl_xor(ls, off, 64);
        invl = 1.f / ls;
        p_lds[h][lane]      = pa;
        p_lds[h][64 + lane] = pb;              // p_lds[h][127] = 0 masks pad in Phase B
    }

    // ---- Phase B: wkv[h][lane] = (sum_n p[n] * kv[n][lane]) / l ----
    {
        float w0 = 0.f, w1 = 0.f, w2 = 0.f, w3 = 0.f;
        #pragma unroll 4
        for (int n4 = 0; n4 < NPAD; n4 += 4) {
            float4 p4 = *(const float4*)&p_lds[h][n4];   // wave-uniform broadcast
            w0 = fmaf(p4.x, kv_lds[n4 + 0][lane], w0);   // stride-64 col reads: 2-way, free
            w1 = fmaf(p4.y, kv_lds[n4 + 1][lane], w1);
            w2 = fmaf(p4.z, kv_lds[n4 + 2][lane], w2);
            w3 = fmaf(p4.w, kv_lds[n4 + 3][lane], w3);
        }
        wkv_lds[h][lane] = ((w0 + w1) + (w2 + w3)) * invl;
    }
    // no barrier: wave-private again

    // ---- Phase C: out[j] = wkv[h,:] . Wv[j,:] ----
    {
        const float4* Wv4 = (const float4*)(Wv + (size_t)tid * KDIM);
        const float4* wv_row = (const float4*)wkv_lds[h];
        float4 oa = {0.f, 0.f, 0.f, 0.f};
        #pragma unroll
        for (int i = 0; i < 16; ++i) {
            float4 w = Wv4[i];
            float4 c = wv_row[i];                        // broadcast
            oa.x = fmaf(c.x, w.x, oa.x);
            oa.y = fmaf(c.y, w.y, oa.y);
            oa.z = fmaf(c.z, w.z, oa.z);
            oa.w = fmaf(c.w, w.w, oa.w);
        }
        out[(size_t)bt * CH + tid] = (oa.x + oa.y) + (oa.z + oa.w);
    }
}

extern "C" void kernel_launch(void* const* d_in, const int* in_sizes, int n_in,
                              void* d_out, int out_size, void* d_ws, size_t ws_size,
                              hipStream_t stream) {
    const float* q_x  = (const float*)d_in[0];
    const float* kv_x = (const float*)d_in[1];
    const float* Wk   = (const float*)d_in[2];
    const float* Wq   = (const float*)d_in[3];
    const float* Wv   = (const float*)d_in[4];
    const float* bias = (const float*)d_in[5];
    const float* Ws   = (const float*)d_in[6];
    const float* bs   = (const float*)d_in[7];
    float* out = (float*)d_out;

    attn_kernel<<<dim3(B * T), dim3(256), 0, stream>>>(
        q_x, kv_x, Wk, Wq, Wv, bias, Ws, bs, out);
}

// Round 3
// 122.628 us; speedup vs baseline: 2.3209x; 2.1757x over previous
//
#include <hip/hip_runtime.h>
#include <math.h>

#define B 8
#define T 128
#define NKEY 127   // t-1
#define NPAD 128   // padded key count (row 127 zeroed, prob forced to 0)
#define KDIM 64    // Q_DIM == KV_DIM
#define NH 4       // heads
#define CH 256     // NH*KDIM output channels

typedef short short8 __attribute__((ext_vector_type(8)));   // 8 bf16 (4 VGPRs)
typedef float floatx4 __attribute__((ext_vector_type(4)));  // MFMA C/D

// tanh(x) = 1 - 2/(e^{2x}+1). Saturates correctly at +/-inf, no clamp needed.
// 5 VALU instrs: mul, exp, add, rcp, fma.
__device__ __forceinline__ float fast_tanh(float x) {
    float e = __expf(2.f * x);
    float r = __builtin_amdgcn_rcpf(e + 1.f);
    return fmaf(-2.f, r, 1.f);
}

// Truncation split: x = hi + lo (+ ~2^-16 rel error), both bf16.
__device__ __forceinline__ void split8(const float4& a, const float4& b,
                                       short8& hi, short8& lo) {
    float x[8] = {a.x, a.y, a.z, a.w, b.x, b.y, b.z, b.w};
    #pragma unroll
    for (int i = 0; i < 8; ++i) {
        unsigned u = __float_as_uint(x[i]);
        hi[i] = (short)(u >> 16);                         // trunc to bf16
        float l = x[i] - __uint_as_float(u & 0xFFFF0000u); // exact residual
        lo[i] = (short)(__float_as_uint(l) >> 16);        // trunc residual
    }
}

// One workgroup per (b,t): 4 waves; wave h == head h.
// Keys GEMM via 3-pass split-bf16 MFMA (fragments from VGPRs -> ~64x fewer
// LDS instructions than R2's broadcast dot-products, which were LDS-pipe bound).
// Phase B (prob-weighted kv) and Phase C (Wv projection) stay exact fp32 VALU.
__global__ __launch_bounds__(256, 2)
void attn_kernel(const float* __restrict__ q_x,   // (B,T,64)
                 const float* __restrict__ kv_x,  // (B,T,127,64)
                 const float* __restrict__ Wk,    // (256,64)
                 const float* __restrict__ Wq,    // (256,64)
                 const float* __restrict__ Wv,    // (256,64)
                 const float* __restrict__ bias,  // (64,)
                 const float* __restrict__ Ws,    // (1,64)
                 const float* __restrict__ bs,    // (1,) -- cancels in softmax
                 float* __restrict__ out)         // (B,T,256)
{
    __shared__ float kv_lds[NPAD][KDIM];                 // 32 KB fp32 (row 127 = 0)
    __shared__ float q_lds[KDIM];                        // 256 B
    __shared__ float qb_lds[CH];                         // 1 KB: query+bias per channel
    __shared__ float p_lds[NH][NPAD];                    // 2 KB: scores then probs
    __shared__ float wkv_lds[NH][KDIM];                  // 1 KB
    __shared__ __align__(16) short bh_lds[16][64][8];    // 16 KB: B-frag hi [nt*2+ks][lane][8]
    __shared__ __align__(16) short bl_lds[16][64][8];    // 16 KB: B-frag lo

    const int bt   = blockIdx.x;
    const int tid  = threadIdx.x;
    const int h    = tid >> 6;
    const int lane = tid & 63;
    const int col  = lane & 15;   // MFMA n / m lane index
    const int quad = lane >> 4;   // MFMA k-group / row-group

    // ---- stage q row + kv tile fp32 (coalesced; zero pad row) ----
    if (tid < KDIM) q_lds[tid] = q_x[(size_t)bt * KDIM + tid];
    {
        const float4* src = (const float4*)(kv_x + (size_t)bt * NKEY * KDIM);
        float4* dst = (float4*)(&kv_lds[0][0]);
        for (int i = tid; i < NPAD * KDIM / 4; i += 256) {
            float4 v = make_float4(0.f, 0.f, 0.f, 0.f);
            if (i < NKEY * KDIM / 4) v = src[i];
            dst[i] = v;
        }
    }
    __syncthreads();

    // ---- query_j + bias -> qb_lds[channel] ----
    {
        const float4* Wq4 = (const float4*)(Wq + (size_t)tid * KDIM);
        float4 qa = {0.f, 0.f, 0.f, 0.f};
        #pragma unroll
        for (int i = 0; i < 16; ++i) {
            float4 w = Wq4[i];
            float4 q4 = ((const float4*)q_lds)[i];
            qa.x = fmaf(q4.x, w.x, qa.x);
            qa.y = fmaf(q4.y, w.y, qa.y);
            qa.z = fmaf(q4.z, w.z, qa.z);
            qa.w = fmaf(q4.w, w.w, qa.w);
        }
        qb_lds[tid] = (qa.x + qa.y) + (qa.z + qa.w) + bias[tid & 63];
    }

    // ---- convert kv -> fragment-ordered bf16 hi/lo LDS regions ----
    // B-fragment layout: lane reads kv[nt*16 + (lane&15)][ks*32 + (lane>>4)*8 + j]
    {
        const int chunk = tid >> 4;          // nt*2+ks, 0..15
        const int ks    = chunk & 1;
        const int nt    = chunk >> 1;
        const int fl0   = (tid & 15) * 4;
        #pragma unroll
        for (int w = 0; w < 4; ++w) {
            int fl = fl0 + w;
            int n  = nt * 16 + (fl & 15);
            int k0 = ks * 32 + (fl >> 4) * 8;
            float4 a = *(const float4*)&kv_lds[n][k0];
            float4 b = *(const float4*)&kv_lds[n][k0 + 4];
            short8 hi, lo;
            split8(a, b, hi, lo);
            *(short8*)&bh_lds[chunk][fl][0] = hi;
            *(short8*)&bl_lds[chunk][fl][0] = lo;
        }
    }
    __syncthreads();

    // ---- A-fragments (Wk rows of this head) from global, split to hi/lo ----
    // A layout: lane holds Wk[h*64 + jt*16 + col][ks*32 + quad*8 + j]
    short8 ahi[4][2], alo[4][2];
    #pragma unroll
    for (int jt = 0; jt < 4; ++jt)
        #pragma unroll
        for (int ks = 0; ks < 2; ++ks) {
            const float* wrow = Wk + (size_t)(h * 64 + jt * 16 + col) * KDIM
                                   + ks * 32 + quad * 8;
            float4 a = *(const float4*)wrow;
            float4 b = *(const float4*)(wrow + 4);
            split8(a, b, ahi[jt][ks], alo[jt][ks]);
        }

    // ---- per-lane qb / ws for epilogue: j = jt*16 + quad*4 + r ----
    float qbv[4][4], wsv[4][4];
    #pragma unroll
    for (int jt = 0; jt < 4; ++jt)
        #pragma unroll
        for (int r = 0; r < 4; ++r) {
            int j = jt * 16 + quad * 4 + r;
            qbv[jt][r] = qb_lds[h * 64 + j];
            wsv[jt][r] = Ws[j];
        }

    // ---- main loop: 8 n-tiles of 16 keys ----
    for (int nt = 0; nt < 8; ++nt) {
        short8 bhi0 = *(const short8*)&bh_lds[nt * 2 + 0][lane][0];
        short8 blo0 = *(const short8*)&bl_lds[nt * 2 + 0][lane][0];
        short8 bhi1 = *(const short8*)&bh_lds[nt * 2 + 1][lane][0];
        short8 blo1 = *(const short8*)&bl_lds[nt * 2 + 1][lane][0];

        floatx4 acc[4];
        #pragma unroll
        for (int jt = 0; jt < 4; ++jt) {
            floatx4 c = {0.f, 0.f, 0.f, 0.f};
            c = __builtin_amdgcn_mfma_f32_16x16x32_bf16(ahi[jt][0], bhi0, c, 0, 0, 0);
            c = __builtin_amdgcn_mfma_f32_16x16x32_bf16(ahi[jt][1], bhi1, c, 0, 0, 0);
            c = __builtin_amdgcn_mfma_f32_16x16x32_bf16(ahi[jt][0], blo0, c, 0, 0, 0);
            c = __builtin_amdgcn_mfma_f32_16x16x32_bf16(ahi[jt][1], blo1, c, 0, 0, 0);
            c = __builtin_amdgcn_mfma_f32_16x16x32_bf16(alo[jt][0], bhi0, c, 0, 0, 0);
            c = __builtin_amdgcn_mfma_f32_16x16x32_bf16(alo[jt][1], bhi1, c, 0, 0, 0);
            acc[jt] = c;
        }

        // epilogue: score[n] = sum_j tanh(key + qb[j]) * ws[j]
        // D layout: col = lane&15 = n within tile, row = quad*4 + r = j within jt
        float partial = 0.f;
        #pragma unroll
        for (int jt = 0; jt < 4; ++jt)
            #pragma unroll
            for (int r = 0; r < 4; ++r)
                partial = fmaf(fast_tanh(acc[jt][r] + qbv[jt][r]), wsv[jt][r], partial);
        partial += __shfl_xor(partial, 16, 64);   // reduce across quads (same col)
        partial += __shfl_xor(partial, 32, 64);
        if (lane < 16) p_lds[h][nt * 16 + lane] = partial;
    }
    // no barrier: wave h is sole writer+reader of p_lds[h][*]

    // ---- softmax over the 127 real keys (2 scores per lane) ----
    float invl;
    {
        float s_a = p_lds[h][lane];
        float s_b = p_lds[h][64 + lane];
        if (lane == 63) s_b = -1e30f;          // mask pad row 127
        float mx = fmaxf(s_a, s_b);
        #pragma unroll
        for (int off = 32; off > 0; off >>= 1)
            mx = fmaxf(mx, __shfl_xor(mx, off, 64));
        float pa = __expf(s_a - mx);
        float pb = __expf(s_b - mx);           // lane 63 -> 0
        float ls = pa + pb;
        #pragma unroll
        for (int off = 32; off > 0; off >>= 1)
            ls += __shfl_xor(ls, off, 64);
        invl = 1.f / ls;
        p_lds[h][lane]      = pa;
        p_lds[h][64 + lane] = pb;              // p_lds[h][127] = 0 masks pad
    }

    // ---- Phase B: wkv[h][lane] = (sum_n p[n] * kv[n][lane]) / l  (exact fp32) ----
    {
        float w0 = 0.f, w1 = 0.f, w2 = 0.f, w3 = 0.f;
        #pragma unroll 4
        for (int n4 = 0; n4 < NPAD; n4 += 4) {
            float4 p4 = *(const float4*)&p_lds[h][n4];   // uniform broadcast
            w0 = fmaf(p4.x, kv_lds[n4 + 0][lane], w0);   // stride-64 cols: 2-way, free
            w1 = fmaf(p4.y, kv_lds[n4 + 1][lane], w1);
            w2 = fmaf(p4.z, kv_lds[n4 + 2][lane], w2);
            w3 = fmaf(p4.w, kv_lds[n4 + 3][lane], w3);
        }
        wkv_lds[h][lane] = ((w0 + w1) + (w2 + w3)) * invl;
    }

    // ---- Phase C: out[j] = wkv[h,:] . Wv[j,:] ----
    {
        const float4* Wv4 = (const float4*)(Wv + (size_t)tid * KDIM);
        const float4* wv_row = (const float4*)wkv_lds[h];
        float4 oa = {0.f, 0.f, 0.f, 0.f};
        #pragma unroll
        for (int i = 0; i < 16; ++i) {
            float4 w = Wv4[i];
            float4 c = wv_row[i];                        // broadcast
            oa.x = fmaf(c.x, w.x, oa.x);
            oa.y = fmaf(c.y, w.y, oa.y);
            oa.z = fmaf(c.z, w.z, oa.z);
            oa.w = fmaf(c.w, w.w, oa.w);
        }
        out[(size_t)bt * CH + tid] = (oa.x + oa.y) + (oa.z + oa.w);
    }
}

extern "C" void kernel_launch(void* const* d_in, const int* in_sizes, int n_in,
                              void* d_out, int out_size, void* d_ws, size_t ws_size,
                              hipStream_t stream) {
    const float* q_x  = (const float*)d_in[0];
    const float* kv_x = (const float*)d_in[1];
    const float* Wk   = (const float*)d_in[2];
    const float* Wq   = (const float*)d_in[3];
    const float* Wv   = (const float*)d_in[4];
    const float* bias = (const float*)d_in[5];
    const float* Ws   = (const float*)d_in[6];
    const float* bs   = (const float*)d_in[7];
    float* out = (float*)d_out;

    attn_kernel<<<dim3(B * T), dim3(256), 0, stream>>>(
        q_x, kv_x, Wk, Wq, Wv, bias, Ws, bs, out);
}